// Round 19
// baseline (881.528 us; speedup 1.0000x reference)
//
#include <hip/hip_runtime.h>
#include <stdint.h>

#define NB   128
#define CIN  3
#define HID  128
#define DEM  256
#define KCB  1024
#define NLAT 32768   // NB*16*16

typedef __bf16 bf16x8 __attribute__((ext_vector_type(8)));
typedef _Float16 f16x8 __attribute__((ext_vector_type(8)));
typedef float  f32x4  __attribute__((ext_vector_type(4)));

__device__ inline unsigned short f2bf(float f) {
    unsigned u = __builtin_bit_cast(unsigned, f);
    u = (u + 0x7fff + ((u >> 16) & 1)) >> 16;
    return (unsigned short)u;
}

// ---------------- zero-fill oh with non-temporal stores --------------------
__global__ __launch_bounds__(256) void k_zero_oh(float* __restrict__ oh, int n4) {
    int t = blockIdx.x * 256 + threadIdx.x;
    f32x4 z = {0.f, 0.f, 0.f, 0.f};
    for (int i = t; i < n4; i += 256 * 2048)
        __builtin_nontemporal_store(z, (f32x4*)(oh + (size_t)i * 4));
}

// ---------------- conv1: x(128,3,64,64) -> hA fp16 hi/lo records, relu -----
__global__ __launch_bounds__(256) void k_conv1(const float* __restrict__ x,
        const float* __restrict__ w, const float* __restrict__ bias,
        unsigned short* __restrict__ hA) {
    __shared__ float sx[3][66][66];
    const int b = blockIdx.y;
    const int ocg = blockIdx.x;
    const int oc0 = ocg * 16;
    const int tid = threadIdx.x;
    for (int i = tid; i < 3 * 66 * 66; i += 256) ((float*)sx)[i] = 0.f;
    __syncthreads();
    const float* xb = x + (size_t)b * (3 * 64 * 64);
    for (int i = tid; i < 3 * 64 * 64; i += 256) {
        int ic = i >> 12; int rem = i & 4095; int y = rem >> 6; int xx = rem & 63;
        sx[ic][y + 1][xx + 1] = xb[i];
    }
    __syncthreads();
    for (int j = 0; j < 4; ++j) {
        int pos = tid + j * 256;
        int oy = pos >> 5, ox = pos & 31;
        float acc[16];
        #pragma unroll
        for (int i = 0; i < 16; ++i) acc[i] = 0.f;
        int iy0 = 2 * oy;
        int ix0 = 2 * ox;
        for (int ic = 0; ic < 3; ++ic) {
            float p[16];
            #pragma unroll
            for (int ky = 0; ky < 4; ++ky)
                #pragma unroll
                for (int kx = 0; kx < 4; ++kx)
                    p[ky * 4 + kx] = sx[ic][iy0 + ky][ix0 + kx];
            #pragma unroll
            for (int oc = 0; oc < 16; ++oc) {
                const float* wp = w + ((oc0 + oc) * 3 + ic) * 16;
                float a = acc[oc];
                #pragma unroll
                for (int t = 0; t < 16; ++t) a = fmaf(p[t], wp[t], a);
                acc[oc] = a;
            }
        }
        unsigned short rec[32];
        #pragma unroll
        for (int oc = 0; oc < 16; ++oc) {
            float v = acc[oc] + bias[oc0 + oc];
            v = v > 0.f ? v : 0.f;
            _Float16 hh = (_Float16)v;
            float hf = (float)hh;
            _Float16 ll = (_Float16)((v - hf) * 2048.0f);
            rec[oc] = __builtin_bit_cast(unsigned short, hh);
            rec[16 + oc] = __builtin_bit_cast(unsigned short, ll);
        }
        uint4* dst = (uint4*)(hA + ((size_t)(b * 8 + ocg) * 1024 + pos) * 32);
        uint4* r4 = (uint4*)rec;
        dst[0] = r4[0]; dst[1] = r4[1]; dst[2] = r4[2]; dst[3] = r4[3];
    }
}

// ---------------- packwf: ew2 OIHW -> fragment-ordered fp16 hi/lo ----------
__global__ void k_packwf(const float* __restrict__ w, unsigned short* __restrict__ wpf) {
    int t = blockIdx.x * 256 + threadIdx.x;   // 32768: (oc 256, c0 8, ci 16)
    int oc = t >> 7, rest = t & 127;
    int c0 = rest >> 4, ci = rest & 15;
    const float* src = w + ((size_t)(oc * 128 + c0 * 16 + ci)) * 16;
    float tv[16];
    #pragma unroll
    for (int i = 0; i < 16; i += 4) {
        float4 v = *(const float4*)(src + i);
        tv[i] = v.x; tv[i + 1] = v.y; tv[i + 2] = v.z; tv[i + 3] = v.w;
    }
    int g = oc >> 4, lr = oc & 15;
    #pragma unroll
    for (int ks = 0; ks < 8; ++ks) {
        int ky = ks >> 1, kxp = ks & 1;
        #pragma unroll
        for (int kxh = 0; kxh < 2; ++kxh) {
            float v = tv[ky * 4 + 2 * kxp + kxh];
            _Float16 hh = (_Float16)v;
            float hf = (float)hh;
            _Float16 ll = (_Float16)((v - hf) * 2048.0f);
            int d = kxh * 16 + ci;
            int hi = d >> 3, el = d & 7;
            size_t base = ((((size_t)(c0 * 8 + ks) * 16 + g) * 2 + 0) * 4 + hi) * 128 + lr * 8 + el;
            wpf[base]       = __builtin_bit_cast(unsigned short, hh);
            wpf[base + 512] = __builtin_bit_cast(unsigned short, ll);   // plane 1
        }
    }
}

// ---------------- conv2 via split-fp16 MFMA: M=128, B regs from global -----
__global__ __launch_bounds__(512) void k_conv2_mfma(const unsigned short* __restrict__ hA,
        const unsigned short* __restrict__ wpf, const float* __restrict__ bias,
        float* __restrict__ e) {
    __shared__ __attribute__((aligned(16))) unsigned short As[577 * 40]; // slot: [16 hi][16 lo][8 pad]
    const int tid = threadIdx.x;
    const int b = blockIdx.y;
    const int ocg = blockIdx.x >> 1, yh = blockIdx.x & 1;
    const int lane = tid & 63, wv = tid >> 6;
    const int wm = wv >> 2, wn = wv & 3;
    const int lr = lane & 15, hi = lane >> 4;

    if (tid < 40) As[576 * 40 + tid] = 0;   // zero slot for x-halo

    f32x4 acc0[4][2], acc1[4][2];
    #pragma unroll
    for (int i = 0; i < 4; ++i)
        #pragma unroll
        for (int j = 0; j < 2; ++j) {
            acc0[i][j] = (f32x4){0.f, 0.f, 0.f, 0.f};
            acc1[i][j] = (f32x4){0.f, 0.f, 0.f, 0.f};
        }

    for (int c0 = 0; c0 < 8; ++c0) {
        __syncthreads();
        {   // stage A: 18 rows x 32 ix x 32 us = 2304 uint4 (pure copy)
            const size_t cbase = (size_t)(b * 8 + c0) * 1024;
            for (int p = tid; p < 2304; p += 512) {
                int l = p >> 7, rem = p & 127;
                int ixs = rem >> 2, q = rem & 3;
                int iy = yh * 16 - 1 + l;
                uint4* dst = (uint4*)(As + (l * 32 + (ixs & 1) * 16 + (ixs >> 1)) * 40 + q * 8);
                if (iy >= 0 && iy < 32)
                    *dst = *(const uint4*)(hA + (cbase + iy * 32 + ixs) * 32 + q * 8);
                else
                    *dst = (uint4){0u, 0u, 0u, 0u};
            }
        }
        __syncthreads();
        #pragma unroll
        for (int ks = 0; ks < 8; ++ks) {
            const int ky = ks >> 1, kxp = ks & 1;
            f16x8 bh[2], bl[2];
            #pragma unroll
            for (int nf = 0; nf < 2; ++nf) {
                const unsigned short* bp = wpf
                    + ((((size_t)(c0 * 8 + ks) * 16 + (ocg * 8 + wn * 2 + nf)) * 2 + 0) * 4 + hi) * 128 + lr * 8;
                bh[nf] = *(const f16x8*)bp;
                bl[nf] = *(const f16x8*)(bp + 512);
            }
            const int o = 2 * kxp - 1 + (hi >> 1);
            const int ix = 2 * lr + o;
            const bool xv = (ix >= 0) && (ix < 32);
            const int sbase = (o & 1) * 16 + (ix >> 1);
            #pragma unroll
            for (int mf = 0; mf < 4; ++mf) {
                int l = 2 * (wm * 4 + mf) + ky;
                int slot = xv ? (l * 32 + sbase) : 576;
                const unsigned short* ap = As + slot * 40 + (hi & 1) * 8;
                f16x8 a0 = *(const f16x8*)ap;          // hi
                f16x8 a1 = *(const f16x8*)(ap + 16);   // lo (x2048)
                #pragma unroll
                for (int nf = 0; nf < 2; ++nf) {
                    acc0[mf][nf] = __builtin_amdgcn_mfma_f32_16x16x32_f16(a0, bh[nf], acc0[mf][nf], 0, 0, 0);
                    acc1[mf][nf] = __builtin_amdgcn_mfma_f32_16x16x32_f16(a0, bl[nf], acc1[mf][nf], 0, 0, 0);
                    acc1[mf][nf] = __builtin_amdgcn_mfma_f32_16x16x32_f16(a1, bh[nf], acc1[mf][nf], 0, 0, 0);
                }
            }
        }
    }
    #pragma unroll
    for (int mf = 0; mf < 4; ++mf) {
        int oy = yh * 8 + wm * 4 + mf;
        #pragma unroll
        for (int nf = 0; nf < 2; ++nf) {
            int oc = ocg * 128 + wn * 32 + nf * 16 + lr;
            float bv = bias[oc];
            #pragma unroll
            for (int r = 0; r < 4; ++r) {
                int ox = hi * 4 + r;
                size_t erow = (size_t)b * 256 + (size_t)oy * 16 + ox;
                e[erow * 256 + oc] = acc0[mf][nf][r] + acc1[mf][nf][r] * (1.0f / 2048.0f) + bv;
            }
        }
    }
}

// ---------------- code norms ----------------
__global__ void k_cnorm(const float* __restrict__ cb, float* __restrict__ cn) {
    int k = blockIdx.x * 256 + threadIdx.x;
    const float* cp = cb + (size_t)k * 256;
    float s = 0.f;
    #pragma unroll 8
    for (int d = 0; d < 256; d += 4) {
        float4 v = *(const float4*)(cp + d);
        s = fmaf(v.x, v.x, s); s = fmaf(v.y, v.y, s);
        s = fmaf(v.z, v.z, s); s = fmaf(v.w, v.w, s);
    }
    cn[k] = s;
}

// ---------------- codebook -> MFMA-fragment-ordered fp16 hi/lo -------------
__global__ void k_packcbp(const float* __restrict__ cb, unsigned short* __restrict__ cbp) {
    int t = blockIdx.x * 256 + threadIdx.x;   // 262144: (code, dim)
    int c = t >> 8, d = t & 255;
    float v = cb[(size_t)c * 256 + d];
    _Float16 hh = (_Float16)v;
    float hf = (float)hh;
    _Float16 ll = (_Float16)((v - hf) * 2048.0f);
    int g = c >> 4, lr = c & 15;
    int kq = d >> 5, rem = d & 31, hi = rem >> 3, el = rem & 7;
    size_t b0 = ((((size_t)(g * 8 + kq) * 2 + 0) * 4 + hi) * 16 + lr) * 8 + el;
    size_t b1 = ((((size_t)(g * 8 + kq) * 2 + 1) * 4 + hi) * 16 + lr) * 8 + el;
    cbp[b0] = __builtin_bit_cast(unsigned short, hh);
    cbp[b1] = __builtin_bit_cast(unsigned short, ll);
}

// ---------------- VQ: M=128 rows/block, argmin scoreboard in LDS -----------
// 8 phases x 1 code-group/wave: acc = 64 VGPR; best lives in redS/redI (LDS),
// updated per phase after a per-mf butterfly (min over (s,code) is order-
// independent -> bit-identical results to the register-scoreboard variants).
// Halves codebook passes (256 blocks x 1 MB) and eliminates the r11 spill.
__global__ __launch_bounds__(512) void k_vq_mfma(const float* __restrict__ e,
        const unsigned short* __restrict__ cbp, const float* __restrict__ cn,
        const float* __restrict__ cb,
        int* __restrict__ idx, int* __restrict__ counts, float* __restrict__ sse,
        float* __restrict__ oh) {
    __shared__ __attribute__((aligned(16))) unsigned short As[128 * 520]; // [256 hi][256 lo][8 pad]
    __shared__ float redS[8][128];
    __shared__ int   redI[8][128];
    __shared__ int   winner[128];
    __shared__ float sred[128];
    const int tid = threadIdx.x;
    const int lane = tid & 63;
    const int wv = tid >> 6;
    const int lr = lane & 15, hi = lane >> 4;
    const int row0 = blockIdx.x * 128;

    #pragma unroll
    for (int rr = 0; rr < 2; ++rr) {   // stage A: 128 rows x 256 k, fp32 -> fp16 hi/lo
        int row = rr * 64 + (tid >> 3), seg = tid & 7;
        const float* src = e + (size_t)(row0 + row) * 256 + seg * 32;
        unsigned short hb[32], lb[32];
        #pragma unroll
        for (int i = 0; i < 32; i += 4) {
            float4 v = *(const float4*)(src + i);
            float vv[4] = {v.x, v.y, v.z, v.w};
            #pragma unroll
            for (int q = 0; q < 4; ++q) {
                _Float16 hh = (_Float16)vv[q];
                float hf = (float)hh;
                _Float16 ll = (_Float16)((vv[q] - hf) * 2048.0f);
                hb[i + q] = __builtin_bit_cast(unsigned short, hh);
                lb[i + q] = __builtin_bit_cast(unsigned short, ll);
            }
        }
        uint4* dh = (uint4*)(As + row * 520 + seg * 32);
        uint4* dl = (uint4*)(As + row * 520 + 256 + seg * 32);
        #pragma unroll
        for (int u = 0; u < 4; ++u) { dh[u] = ((uint4*)hb)[u]; dl[u] = ((uint4*)lb)[u]; }
    }
    // init scoreboard
    for (int i = tid; i < 8 * 128; i += 512) {
        redS[i >> 7][i & 127] = 3.4e38f;
        redI[i >> 7][i & 127] = 0;
    }
    __syncthreads();

    for (int ph = 0; ph < 8; ++ph) {
        const int gidx = ph * 8 + wv;        // this wave's 16-code fragment group
        const int code = gidx * 16 + lr;
        f32x4 acc0[8], acc1[8];
        #pragma unroll
        for (int i = 0; i < 8; ++i) {
            acc0[i] = (f32x4){0.f, 0.f, 0.f, 0.f};
            acc1[i] = (f32x4){0.f, 0.f, 0.f, 0.f};
        }
        #pragma unroll
        for (int kq = 0; kq < 8; ++kq) {
            const unsigned short* bp = cbp
                + (((size_t)(gidx * 8 + kq) * 2 + 0) * 4 + hi) * 128 + lr * 8;
            f16x8 bh = *(const f16x8*)bp;
            f16x8 bl = *(const f16x8*)(bp + 512);   // plane 1 offset = 4*16*8
            #pragma unroll
            for (int mf = 0; mf < 8; ++mf) {
                const unsigned short* ap = As + (mf * 16 + lr) * 520 + kq * 32 + hi * 8;
                f16x8 a0 = *(const f16x8*)ap;          // hi
                f16x8 a1 = *(const f16x8*)(ap + 256);  // lo (x2048)
                acc0[mf] = __builtin_amdgcn_mfma_f32_16x16x32_f16(a0, bh, acc0[mf], 0, 0, 0);
                acc1[mf] = __builtin_amdgcn_mfma_f32_16x16x32_f16(a0, bl, acc1[mf], 0, 0, 0);
                acc1[mf] = __builtin_amdgcn_mfma_f32_16x16x32_f16(a1, bh, acc1[mf], 0, 0, 0);
            }
        }
        // fold per mf: butterfly over the 16 code-columns, then LDS scoreboard
        const float cnv = cn[code];
        #pragma unroll
        for (int mf = 0; mf < 8; ++mf) {
            float ps[4]; int pi[4];
            #pragma unroll
            for (int r = 0; r < 4; ++r) {
                float dot = fmaf(acc1[mf][r], (1.0f / 2048.0f), acc0[mf][r]);
                ps[r] = fmaf(-2.0f, dot, cnv);
                pi[r] = code;
            }
            #pragma unroll
            for (int m = 1; m < 16; m <<= 1) {
                #pragma unroll
                for (int r = 0; r < 4; ++r) {
                    float os = __shfl_xor(ps[r], m, 64);
                    int   oi = __shfl_xor(pi[r], m, 64);
                    if (os < ps[r] || (os == ps[r] && oi < pi[r])) { ps[r] = os; pi[r] = oi; }
                }
            }
            if (lr == 0) {
                #pragma unroll
                for (int r = 0; r < 4; ++r) {
                    int row = mf * 16 + hi * 4 + r;
                    float cs = redS[wv][row]; int ci2 = redI[wv][row];
                    if (ps[r] < cs || (ps[r] == cs && pi[r] < ci2)) {
                        redS[wv][row] = ps[r]; redI[wv][row] = pi[r];
                    }
                }
            }
        }
    }
    __syncthreads();
    if (tid < 128) {
        float bs = redS[0][tid]; int bi = redI[0][tid];
        for (int ww = 1; ww < 8; ++ww) {
            float s = redS[ww][tid]; int i2 = redI[ww][tid];
            if (s < bs || (s == bs && i2 < bi)) { bs = s; bi = i2; }
        }
        int rowg = row0 + tid;
        idx[rowg] = bi;
        atomicAdd(counts + bi, 1);
        int bimg = rowg >> 8, n = rowg & 255;
        __builtin_nontemporal_store(1.0f,
            oh + (size_t)bimg * (KCB * 256) + (size_t)bi * 256 + n);
        winner[tid] = bi;
    }
    __syncthreads();
    {   // exact fp32 SSE for the winners: 4 threads/row x 64 dims
        int row = tid >> 2, seg = tid & 3;
        int bi = winner[row];
        const float* cp = cb + (size_t)bi * 256 + seg * 64;
        const float* ep = e + (size_t)(row0 + row) * 256 + seg * 64;
        float s = 0.f;
        #pragma unroll
        for (int i = 0; i < 64; i += 4) {
            float4 a = *(const float4*)(cp + i);
            float4 b = *(const float4*)(ep + i);
            float d0 = a.x - b.x, d1 = a.y - b.y, d2 = a.z - b.z, d3 = a.w - b.w;
            s = fmaf(d0, d0, s); s = fmaf(d1, d1, s);
            s = fmaf(d2, d2, s); s = fmaf(d3, d3, s);
        }
        s += __shfl_down(s, 2, 64);
        s += __shfl_down(s, 1, 64);
        if ((tid & 3) == 0) sred[row] = s;
    }
    __syncthreads();
    if (tid == 0) {
        float t = 0.f;
        for (int i = 0; i < 128; ++i) t += sred[i];
        atomicAdd(sse, t);
    }
}

// ---------------- prepack: codebook -> bf16 (for convT1) -------------------
__global__ void k_cb2bf(const float* __restrict__ cb, unsigned short* __restrict__ cbb) {
    int t = blockIdx.x * 256 + threadIdx.x;
    float4 v = *(const float4*)(cb + (size_t)t * 4);
    ushort4 o;
    o.x = f2bf(v.x); o.y = f2bf(v.y); o.z = f2bf(v.z); o.w = f2bf(v.w);
    *(ushort4*)(cbb + (size_t)t * 4) = o;
}

// ---------------- prepack: dec_w1 -> Wp[p][tap][oc][ci] bf16 ----------------
__global__ void k_packw(const float* __restrict__ w, unsigned short* __restrict__ wp) {
    int t = blockIdx.x * 256 + threadIdx.x;
    int ci = t >> 7, oc = t & 127;
    const float* src = w + ((size_t)ci * 128 + oc) * 16;
    float tv[16];
    #pragma unroll
    for (int i = 0; i < 16; i += 4) {
        float4 v = *(const float4*)(src + i);
        tv[i] = v.x; tv[i + 1] = v.y; tv[i + 2] = v.z; tv[i + 3] = v.w;
    }
    #pragma unroll
    for (int p = 0; p < 4; ++p) {
        int a = p >> 1, b2 = p & 1;
        #pragma unroll
        for (int tap = 0; tap < 4; ++tap) {
            int dy = tap >> 1, dx = tap & 1;
            float v = tv[((1 - a) + 2 * dy) * 4 + (1 - b2) + 2 * dx];
            wp[((((p * 4 + tap) * 128) + oc) << 8) + ci] = f2bf(v);
        }
    }
}

// ---------------- packw2t: dw2 (128,3,4,4) -> convt2 B-frag table bf16 -----
__global__ void k_packw2t(const float* __restrict__ w, unsigned short* __restrict__ wt) {
    int t = blockIdx.x * 256 + threadIdx.x;    // 32768
    int el = t & 7, lr = (t >> 3) & 15, hi = (t >> 7) & 3;
    int cig = (t >> 9) & 3, tp = (t >> 11) & 3, p = (t >> 13) & 3;
    int ci = cig * 32 + hi * 8 + el;
    int a = p >> 1, bb = p & 1;
    int ky0 = 1 - a, kx0 = 1 - bb;
    int wtap;
    if (tp == 0) wtap = ky0 * 4 + kx0;
    else if (tp == 1) wtap = ky0 * 4 + kx0 + 2;
    else if (tp == 2) wtap = (ky0 + 2) * 4 + kx0;
    else wtap = (ky0 + 2) * 4 + kx0 + 2;
    unsigned short v = 0;
    if (lr < 3) v = f2bf(w[((size_t)ci * 3 + lr) * 16 + wtap]);
    wt[t] = v;
}

// ---------------- convT1 via MFMA -> d1b bf16 [b][y][x][ci], relu ----------
__global__ __launch_bounds__(512) void k_convt1_mfma(const int* __restrict__ idx,
        const unsigned short* __restrict__ cbb, const unsigned short* __restrict__ wp,
        const float* __restrict__ bias, unsigned short* __restrict__ d1b) {
    __shared__ unsigned short As[257 * 72];
    __shared__ unsigned short Bs[128 * 72];
    __shared__ int sidx[256];
    const int tid = threadIdx.x;
    const int b  = blockIdx.y;
    const int p  = blockIdx.x;
    const int a  = p >> 1, bb2 = p & 1;
    if (tid < 256) sidx[tid] = idx[b * 256 + tid] * 256;
    if (tid < 72)  As[256 * 72 + tid] = 0;
    const int lane = tid & 63;
    const int w    = tid >> 6;
    const int wm = w >> 2, wn = w & 3;
    const int lr = lane & 15, hi = lane >> 4;
    const int koff = hi * 8;
    f32x4 acc[8][2];
    #pragma unroll
    for (int i = 0; i < 8; ++i)
        #pragma unroll
        for (int j = 0; j < 2; ++j) acc[i][j] = (f32x4){0.f, 0.f, 0.f, 0.f};

    for (int c0 = 0; c0 < 256; c0 += 64) {
        for (int tap = 0; tap < 4; ++tap) {
            __syncthreads();
            if (tap == 0) {
                int row = tid >> 1, half = tid & 1;
                const uint4* src = (const uint4*)(cbb + sidx[row] + c0 + half * 32);
                uint4 v0 = src[0], v1 = src[1], v2 = src[2], v3 = src[3];
                uint4* dst = (uint4*)(As + row * 72 + half * 32);
                dst[0] = v0; dst[1] = v1; dst[2] = v2; dst[3] = v3;
            }
            {
                int oc = tid >> 2, q = tid & 3;
                const uint4* src = (const uint4*)(wp + (((p * 4 + tap) * 128 + oc) << 8) + c0 + q * 16);
                uint4 v0 = src[0], v1 = src[1];
                uint4* dst = (uint4*)(Bs + oc * 72 + q * 16);
                dst[0] = v0; dst[1] = v1;
            }
            __syncthreads();
            const int dy = tap >> 1, dx = tap & 1;
            const int xo = lr + bb2 - dx;
            const bool xv = (xo >= 0) && (xo < 16);
            #pragma unroll
            for (int kk = 0; kk < 2; ++kk) {
                bf16x8 aF[8];
                #pragma unroll
                for (int i = 0; i < 8; ++i) {
                    int typ = wm * 8 + i + a - dy;
                    int row = (xv && typ >= 0 && typ < 16) ? typ * 16 + xo : 256;
                    aF[i] = *(const bf16x8*)(As + row * 72 + kk * 32 + koff);
                }
                #pragma unroll
                for (int j = 0; j < 2; ++j) {
                    bf16x8 bF = *(const bf16x8*)(Bs + ((wn * 2 + j) * 16 + lr) * 72 + kk * 32 + koff);
                    #pragma unroll
                    for (int i = 0; i < 8; ++i)
                        acc[i][j] = __builtin_amdgcn_mfma_f32_16x16x32_bf16(aF[i], bF, acc[i][j], 0, 0, 0);
                }
            }
        }
    }
    #pragma unroll
    for (int j = 0; j < 2; ++j) {
        int oc = (wn * 2 + j) * 16 + lr;
        float bv = bias[oc];
        #pragma unroll
        for (int i = 0; i < 8; ++i) {
            int mt = wm * 8 + i;
            int oy = 2 * mt + a;
            #pragma unroll
            for (int r = 0; r < 4; ++r) {
                int ox = bb2 + 2 * (hi * 4 + r);
                float v = acc[i][j][r] + bv;
                v = v > 0.f ? v : 0.f;
                d1b[(((size_t)b * 32 + oy) * 32 + ox) * 128 + oc] = f2bf(v);
            }
        }
    }
}

// ---------------- convT2 via MFMA: d1b -> x_hat ----------------------------
__global__ __launch_bounds__(512) void k_convt2_mfma(const unsigned short* __restrict__ d1b,
        const unsigned short* __restrict__ wt, const float* __restrict__ bias,
        float* __restrict__ xhat) {
    __shared__ __attribute__((aligned(16))) unsigned short sd[18 * 34 * 32]; // [l][xx][ci32]
    const int tid = threadIdx.x;
    const int b = blockIdx.y;
    const int p = blockIdx.x >> 1, yh = blockIdx.x & 1;
    const int a = p >> 1, bb = p & 1;
    const int lane = tid & 63, wv = tid >> 6;
    const int lr = lane & 15, hi = lane >> 4;

    f32x4 acc[4];
    #pragma unroll
    for (int i = 0; i < 4; ++i) acc[i] = (f32x4){0.f, 0.f, 0.f, 0.f};

    for (int cig = 0; cig < 4; ++cig) {
        __syncthreads();
        for (int q4 = tid; q4 < 2448; q4 += 512) {       // 18*34*4 uint4
            int l = q4 / 136, rem = q4 % 136, xx = rem >> 2, q = rem & 3;
            int iy = yh * 16 - 1 + l, ixx = xx - 1;
            uint4* dst = (uint4*)(sd + (l * 34 + xx) * 32 + q * 8);
            if (iy >= 0 && iy < 32 && ixx >= 0 && ixx < 32)
                *dst = *(const uint4*)(d1b + (((size_t)b * 32 + iy) * 32 + ixx) * 128 + cig * 32 + q * 8);
            else
                *dst = (uint4){0u, 0u, 0u, 0u};
        }
        __syncthreads();
        #pragma unroll
        for (int tp = 0; tp < 4; ++tp) {
            const unsigned short* bp = wt + ((((p * 4 + tp) * 4 + cig) * 4 + hi) * 16 + lr) * 8;
            bf16x8 bF = *(const bf16x8*)bp;
            #pragma unroll
            for (int mf = 0; mf < 4; ++mf) {
                int pos = wv * 64 + mf * 16 + lr;
                int myl = pos >> 5, mx = pos & 31;
                int l = myl + a + (tp < 2 ? 1 : 0);
                int xx = mx + bb + ((tp & 1) ? 0 : 1);
                bf16x8 aF = *(const bf16x8*)(sd + (l * 34 + xx) * 32 + hi * 8);
                acc[mf] = __builtin_amdgcn_mfma_f32_16x16x32_bf16(aF, bF, acc[mf], 0, 0, 0);
            }
        }
    }
    if (lr < 3) {
        float bv = bias[lr];
        #pragma unroll
        for (int mf = 0; mf < 4; ++mf) {
            #pragma unroll
            for (int r = 0; r < 4; ++r) {
                int pos = wv * 64 + mf * 16 + hi * 4 + r;
                int oy = 2 * (yh * 16 + (pos >> 5)) + a;
                int ox = 2 * (pos & 31) + bb;
                xhat[(((size_t)b * 3 + lr) * 64 + oy) * 64 + ox] = acc[mf][r] + bv;
            }
        }
    }
}

// ---------------- finalize: loss + perplexity ------------------------------
__global__ void k_final(const int* __restrict__ counts, const float* __restrict__ sse,
                        float* __restrict__ out_loss, float* __restrict__ out_perp) {
    __shared__ float red[256];
    int tid = threadIdx.x;
    float s = 0.f;
    for (int k = tid; k < 1024; k += 256) {
        float p = (float)counts[k] * (1.f / 32768.f);
        s += p * logf(p + 1e-10f);
    }
    red[tid] = s;
    __syncthreads();
    for (int st = 128; st > 0; st >>= 1) {
        if (tid < st) red[tid] += red[tid + st];
        __syncthreads();
    }
    if (tid == 0) {
        *out_perp = expf(-red[0]);
        *out_loss = 0.25f * (*sse) / 8388608.0f;
    }
}

extern "C" void kernel_launch(void* const* d_in, const int* in_sizes, int n_in,
                              void* d_out, int out_size, void* d_ws, size_t ws_size,
                              hipStream_t stream) {
    const float* x   = (const float*)d_in[0];
    const float* ew1 = (const float*)d_in[1];
    const float* eb1 = (const float*)d_in[2];
    const float* ew2 = (const float*)d_in[3];
    const float* eb2 = (const float*)d_in[4];
    const float* dw1 = (const float*)d_in[5];
    const float* db1 = (const float*)d_in[6];
    const float* dw2 = (const float*)d_in[7];
    const float* db2 = (const float*)d_in[8];
    const float* cb  = (const float*)d_in[9];

    float* out  = (float*)d_out;
    float* xhat = out;                       // 128*3*64*64 = 1572864
    float* loss = out + 1572864;
    float* perp = out + 1572865;
    float* oh   = out + 1572866;             // 128*1024*256 = 33554432

    char* ws = (char*)d_ws;
    unsigned short* hA = (unsigned short*)ws;                 // 64 MB (dead after conv2)
    float* e      = (float*)(ws + (size_t)64 * 1024 * 1024);  // 32 MB (dead after vq)
    int*   idx    = (int*)(ws + (size_t)96 * 1024 * 1024);    // 128 KB
    int*   counts = idx + NLAT;                               // 4 KB
    float* sse    = (float*)(counts + KCB);                   // 4 B
    float* cn     = sse + 1;                                  // 4 KB
    unsigned short* cbp = (unsigned short*)ws;                // 1 MB (after conv2)
    unsigned short* d1b = (unsigned short*)ws;                // 32 MB (after vq; clobbers cbp)
    unsigned short* cbb = (unsigned short*)e;                 // 512 KB (after vq)
    unsigned short* wpk = (unsigned short*)(ws + (size_t)65 * 1024 * 1024);  // 1 MB (after vq)
    unsigned short* wt  = (unsigned short*)(ws + (size_t)67 * 1024 * 1024);  // 64 KB (after vq)
    unsigned short* wpf = (unsigned short*)(((uintptr_t)oh + 15) & ~(uintptr_t)15);  // 2 MB in oh region

    hipMemsetAsync(counts, 0, KCB * 4 + 4, stream);

    k_cnorm<<<4, 256, 0, stream>>>(cb, cn);
    k_packwf<<<128, 256, 0, stream>>>(ew2, wpf);               // dirties oh[0:2MB]
    k_conv1<<<dim3(8, 128), 256, 0, stream>>>(x, ew1, eb1, hA);
    k_zero_oh<<<2048, 256, 0, stream>>>(oh + 524304, (33554432 - 524304) / 4);  // beyond wpf slice
    k_conv2_mfma<<<dim3(4, 128), 512, 0, stream>>>(hA, wpf, eb2, e);
    k_zero_oh<<<64, 256, 0, stream>>>(oh, 524304 / 4);          // re-zero wpf slice
    k_packcbp<<<1024, 256, 0, stream>>>(cb, cbp);              // hA region now dead
    k_vq_mfma<<<256, 512, 0, stream>>>(e, cbp, cn, cb, idx, counts, sse, oh);
    k_cb2bf<<<256, 256, 0, stream>>>(cb, cbb);
    k_packw<<<128, 256, 0, stream>>>(dw1, wpk);
    k_packw2t<<<128, 256, 0, stream>>>(dw2, wt);
    k_convt1_mfma<<<dim3(4, 128), 512, 0, stream>>>(idx, cbb, wpk, db1, d1b);  // clobbers cbp (dead)
    k_convt2_mfma<<<dim3(8, 128), 512, 0, stream>>>(d1b, wt, db2, xhat);
    k_final<<<1, 256, 0, stream>>>(counts, sse, loss, perp);
}

// Round 20
// 583.199 us; speedup vs baseline: 1.5115x; 1.5115x over previous
//
#include <hip/hip_runtime.h>
#include <stdint.h>

#define NB   128
#define CIN  3
#define HID  128
#define DEM  256
#define KCB  1024
#define NLAT 32768   // NB*16*16

typedef __bf16 bf16x8 __attribute__((ext_vector_type(8)));
typedef _Float16 f16x8 __attribute__((ext_vector_type(8)));
typedef float  f32x4  __attribute__((ext_vector_type(4)));

__device__ inline unsigned short f2bf(float f) {
    unsigned u = __builtin_bit_cast(unsigned, f);
    u = (u + 0x7fff + ((u >> 16) & 1)) >> 16;
    return (unsigned short)u;
}

// ---------------- zero-fill oh with non-temporal stores --------------------
__global__ __launch_bounds__(256) void k_zero_oh(float* __restrict__ oh, int n4) {
    int t = blockIdx.x * 256 + threadIdx.x;
    f32x4 z = {0.f, 0.f, 0.f, 0.f};
    for (int i = t; i < n4; i += 256 * 2048)
        __builtin_nontemporal_store(z, (f32x4*)(oh + (size_t)i * 4));
}

// ---------------- conv1: x(128,3,64,64) -> hA fp16 hi/lo records, relu -----
__global__ __launch_bounds__(256) void k_conv1(const float* __restrict__ x,
        const float* __restrict__ w, const float* __restrict__ bias,
        unsigned short* __restrict__ hA) {
    __shared__ float sx[3][66][66];
    const int b = blockIdx.y;
    const int ocg = blockIdx.x;
    const int oc0 = ocg * 16;
    const int tid = threadIdx.x;
    for (int i = tid; i < 3 * 66 * 66; i += 256) ((float*)sx)[i] = 0.f;
    __syncthreads();
    const float* xb = x + (size_t)b * (3 * 64 * 64);
    for (int i = tid; i < 3 * 64 * 64; i += 256) {
        int ic = i >> 12; int rem = i & 4095; int y = rem >> 6; int xx = rem & 63;
        sx[ic][y + 1][xx + 1] = xb[i];
    }
    __syncthreads();
    for (int j = 0; j < 4; ++j) {
        int pos = tid + j * 256;
        int oy = pos >> 5, ox = pos & 31;
        float acc[16];
        #pragma unroll
        for (int i = 0; i < 16; ++i) acc[i] = 0.f;
        int iy0 = 2 * oy;
        int ix0 = 2 * ox;
        for (int ic = 0; ic < 3; ++ic) {
            float p[16];
            #pragma unroll
            for (int ky = 0; ky < 4; ++ky)
                #pragma unroll
                for (int kx = 0; kx < 4; ++kx)
                    p[ky * 4 + kx] = sx[ic][iy0 + ky][ix0 + kx];
            #pragma unroll
            for (int oc = 0; oc < 16; ++oc) {
                const float* wp = w + ((oc0 + oc) * 3 + ic) * 16;
                float a = acc[oc];
                #pragma unroll
                for (int t = 0; t < 16; ++t) a = fmaf(p[t], wp[t], a);
                acc[oc] = a;
            }
        }
        unsigned short rec[32];
        #pragma unroll
        for (int oc = 0; oc < 16; ++oc) {
            float v = acc[oc] + bias[oc0 + oc];
            v = v > 0.f ? v : 0.f;
            _Float16 hh = (_Float16)v;
            float hf = (float)hh;
            _Float16 ll = (_Float16)((v - hf) * 2048.0f);
            rec[oc] = __builtin_bit_cast(unsigned short, hh);
            rec[16 + oc] = __builtin_bit_cast(unsigned short, ll);
        }
        uint4* dst = (uint4*)(hA + ((size_t)(b * 8 + ocg) * 1024 + pos) * 32);
        uint4* r4 = (uint4*)rec;
        dst[0] = r4[0]; dst[1] = r4[1]; dst[2] = r4[2]; dst[3] = r4[3];
    }
}

// ---------------- packwf: ew2 OIHW -> fragment-ordered fp16 hi/lo ----------
__global__ void k_packwf(const float* __restrict__ w, unsigned short* __restrict__ wpf) {
    int t = blockIdx.x * 256 + threadIdx.x;   // 32768: (oc 256, c0 8, ci 16)
    int oc = t >> 7, rest = t & 127;
    int c0 = rest >> 4, ci = rest & 15;
    const float* src = w + ((size_t)(oc * 128 + c0 * 16 + ci)) * 16;
    float tv[16];
    #pragma unroll
    for (int i = 0; i < 16; i += 4) {
        float4 v = *(const float4*)(src + i);
        tv[i] = v.x; tv[i + 1] = v.y; tv[i + 2] = v.z; tv[i + 3] = v.w;
    }
    int g = oc >> 4, lr = oc & 15;
    #pragma unroll
    for (int ks = 0; ks < 8; ++ks) {
        int ky = ks >> 1, kxp = ks & 1;
        #pragma unroll
        for (int kxh = 0; kxh < 2; ++kxh) {
            float v = tv[ky * 4 + 2 * kxp + kxh];
            _Float16 hh = (_Float16)v;
            float hf = (float)hh;
            _Float16 ll = (_Float16)((v - hf) * 2048.0f);
            int d = kxh * 16 + ci;
            int hi = d >> 3, el = d & 7;
            size_t base = ((((size_t)(c0 * 8 + ks) * 16 + g) * 2 + 0) * 4 + hi) * 128 + lr * 8 + el;
            wpf[base]       = __builtin_bit_cast(unsigned short, hh);
            wpf[base + 512] = __builtin_bit_cast(unsigned short, ll);   // plane 1
        }
    }
}

// ---------------- conv2 via split-fp16 MFMA: M=128, B regs from global -----
__global__ __launch_bounds__(512) void k_conv2_mfma(const unsigned short* __restrict__ hA,
        const unsigned short* __restrict__ wpf, const float* __restrict__ bias,
        float* __restrict__ e) {
    __shared__ __attribute__((aligned(16))) unsigned short As[577 * 40]; // slot: [16 hi][16 lo][8 pad]
    const int tid = threadIdx.x;
    const int b = blockIdx.y;
    const int ocg = blockIdx.x >> 1, yh = blockIdx.x & 1;
    const int lane = tid & 63, wv = tid >> 6;
    const int wm = wv >> 2, wn = wv & 3;
    const int lr = lane & 15, hi = lane >> 4;

    if (tid < 40) As[576 * 40 + tid] = 0;   // zero slot for x-halo

    f32x4 acc0[4][2], acc1[4][2];
    #pragma unroll
    for (int i = 0; i < 4; ++i)
        #pragma unroll
        for (int j = 0; j < 2; ++j) {
            acc0[i][j] = (f32x4){0.f, 0.f, 0.f, 0.f};
            acc1[i][j] = (f32x4){0.f, 0.f, 0.f, 0.f};
        }

    for (int c0 = 0; c0 < 8; ++c0) {
        __syncthreads();
        {   // stage A: 18 rows x 32 ix x 32 us = 2304 uint4 (pure copy)
            const size_t cbase = (size_t)(b * 8 + c0) * 1024;
            for (int p = tid; p < 2304; p += 512) {
                int l = p >> 7, rem = p & 127;
                int ixs = rem >> 2, q = rem & 3;
                int iy = yh * 16 - 1 + l;
                uint4* dst = (uint4*)(As + (l * 32 + (ixs & 1) * 16 + (ixs >> 1)) * 40 + q * 8);
                if (iy >= 0 && iy < 32)
                    *dst = *(const uint4*)(hA + (cbase + iy * 32 + ixs) * 32 + q * 8);
                else
                    *dst = (uint4){0u, 0u, 0u, 0u};
            }
        }
        __syncthreads();
        #pragma unroll
        for (int ks = 0; ks < 8; ++ks) {
            const int ky = ks >> 1, kxp = ks & 1;
            f16x8 bh[2], bl[2];
            #pragma unroll
            for (int nf = 0; nf < 2; ++nf) {
                const unsigned short* bp = wpf
                    + ((((size_t)(c0 * 8 + ks) * 16 + (ocg * 8 + wn * 2 + nf)) * 2 + 0) * 4 + hi) * 128 + lr * 8;
                bh[nf] = *(const f16x8*)bp;
                bl[nf] = *(const f16x8*)(bp + 512);
            }
            const int o = 2 * kxp - 1 + (hi >> 1);
            const int ix = 2 * lr + o;
            const bool xv = (ix >= 0) && (ix < 32);
            const int sbase = (o & 1) * 16 + (ix >> 1);
            #pragma unroll
            for (int mf = 0; mf < 4; ++mf) {
                int l = 2 * (wm * 4 + mf) + ky;
                int slot = xv ? (l * 32 + sbase) : 576;
                const unsigned short* ap = As + slot * 40 + (hi & 1) * 8;
                f16x8 a0 = *(const f16x8*)ap;          // hi
                f16x8 a1 = *(const f16x8*)(ap + 16);   // lo (x2048)
                #pragma unroll
                for (int nf = 0; nf < 2; ++nf) {
                    acc0[mf][nf] = __builtin_amdgcn_mfma_f32_16x16x32_f16(a0, bh[nf], acc0[mf][nf], 0, 0, 0);
                    acc1[mf][nf] = __builtin_amdgcn_mfma_f32_16x16x32_f16(a0, bl[nf], acc1[mf][nf], 0, 0, 0);
                    acc1[mf][nf] = __builtin_amdgcn_mfma_f32_16x16x32_f16(a1, bh[nf], acc1[mf][nf], 0, 0, 0);
                }
            }
        }
    }
    #pragma unroll
    for (int mf = 0; mf < 4; ++mf) {
        int oy = yh * 8 + wm * 4 + mf;
        #pragma unroll
        for (int nf = 0; nf < 2; ++nf) {
            int oc = ocg * 128 + wn * 32 + nf * 16 + lr;
            float bv = bias[oc];
            #pragma unroll
            for (int r = 0; r < 4; ++r) {
                int ox = hi * 4 + r;
                size_t erow = (size_t)b * 256 + (size_t)oy * 16 + ox;
                e[erow * 256 + oc] = acc0[mf][nf][r] + acc1[mf][nf][r] * (1.0f / 2048.0f) + bv;
            }
        }
    }
}

// ---------------- code norms ----------------
__global__ void k_cnorm(const float* __restrict__ cb, float* __restrict__ cn) {
    int k = blockIdx.x * 256 + threadIdx.x;
    const float* cp = cb + (size_t)k * 256;
    float s = 0.f;
    #pragma unroll 8
    for (int d = 0; d < 256; d += 4) {
        float4 v = *(const float4*)(cp + d);
        s = fmaf(v.x, v.x, s); s = fmaf(v.y, v.y, s);
        s = fmaf(v.z, v.z, s); s = fmaf(v.w, v.w, s);
    }
    cn[k] = s;
}

// ---------------- codebook -> MFMA-fragment-ordered fp16 hi/lo -------------
__global__ void k_packcbp(const float* __restrict__ cb, unsigned short* __restrict__ cbp) {
    int t = blockIdx.x * 256 + threadIdx.x;   // 262144: (code, dim)
    int c = t >> 8, d = t & 255;
    float v = cb[(size_t)c * 256 + d];
    _Float16 hh = (_Float16)v;
    float hf = (float)hh;
    _Float16 ll = (_Float16)((v - hf) * 2048.0f);
    int g = c >> 4, lr = c & 15;
    int kq = d >> 5, rem = d & 31, hi = rem >> 3, el = rem & 7;
    size_t b0 = ((((size_t)(g * 8 + kq) * 2 + 0) * 4 + hi) * 16 + lr) * 8 + el;
    size_t b1 = ((((size_t)(g * 8 + kq) * 2 + 1) * 4 + hi) * 16 + lr) * 8 + el;
    cbp[b0] = __builtin_bit_cast(unsigned short, hh);
    cbp[b1] = __builtin_bit_cast(unsigned short, ll);
}

// ---------------- VQ via split-fp16 MFMA (r11 form — empirical optimum) ----
__global__ __launch_bounds__(512) void k_vq_mfma(const float* __restrict__ e,
        const unsigned short* __restrict__ cbp, const float* __restrict__ cn,
        const float* __restrict__ cb,
        int* __restrict__ idx, int* __restrict__ counts, float* __restrict__ sse,
        float* __restrict__ oh) {
    __shared__ __attribute__((aligned(16))) unsigned short As[64 * 520]; // [256 hi][256 lo][8 pad]
    __shared__ float redS[8][64];
    __shared__ int   redI[8][64];
    __shared__ int   winner[64];
    __shared__ float sred[64];
    const int tid = threadIdx.x;
    const int lane = tid & 63;
    const int wv = tid >> 6;
    const int lr = lane & 15, hi = lane >> 4;
    const int row0 = blockIdx.x * 64;

    {   // stage A once: 64 rows x 256 k, fp32 -> fp16 hi/lo
        int row = tid >> 3, seg = tid & 7;
        const float* src = e + (size_t)(row0 + row) * 256 + seg * 32;
        unsigned short hb[32], lb[32];
        #pragma unroll
        for (int i = 0; i < 32; i += 4) {
            float4 v = *(const float4*)(src + i);
            float vv[4] = {v.x, v.y, v.z, v.w};
            #pragma unroll
            for (int q = 0; q < 4; ++q) {
                _Float16 hh = (_Float16)vv[q];
                float hf = (float)hh;
                _Float16 ll = (_Float16)((vv[q] - hf) * 2048.0f);
                hb[i + q] = __builtin_bit_cast(unsigned short, hh);
                lb[i + q] = __builtin_bit_cast(unsigned short, ll);
            }
        }
        uint4* dh = (uint4*)(As + row * 520 + seg * 32);
        uint4* dl = (uint4*)(As + row * 520 + 256 + seg * 32);
        #pragma unroll
        for (int u = 0; u < 4; ++u) { dh[u] = ((uint4*)hb)[u]; dl[u] = ((uint4*)lb)[u]; }
    }
    __syncthreads();

    float best_s[4][4];
    int   best_i[4][4];
    #pragma unroll
    for (int a = 0; a < 4; ++a)
        #pragma unroll
        for (int r = 0; r < 4; ++r) { best_s[a][r] = 3.4e38f; best_i[a][r] = 0; }

    for (int ncg = 0; ncg < 4; ++ncg) {
        f32x4 acc0[4][2], acc1[4][2];
        #pragma unroll
        for (int i = 0; i < 4; ++i)
            #pragma unroll
            for (int j = 0; j < 2; ++j) {
                acc0[i][j] = (f32x4){0.f, 0.f, 0.f, 0.f};
                acc1[i][j] = (f32x4){0.f, 0.f, 0.f, 0.f};
            }
        const int gbase = ncg * 16 + wv * 2;     // fragment group of 16 codes
        #pragma unroll
        for (int kq = 0; kq < 8; ++kq) {
            f16x8 bh[2], bl[2];
            #pragma unroll
            for (int nf = 0; nf < 2; ++nf) {
                const unsigned short* bp = cbp
                    + (((size_t)((gbase + nf) * 8 + kq) * 2 + 0) * 4 + hi) * 128 + lr * 8;
                bh[nf] = *(const f16x8*)bp;
                bl[nf] = *(const f16x8*)(bp + 512);
            }
            #pragma unroll
            for (int mf = 0; mf < 4; ++mf) {
                const unsigned short* ap = As + (mf * 16 + lr) * 520 + kq * 32 + hi * 8;
                f16x8 a0 = *(const f16x8*)ap;          // hi
                f16x8 a1 = *(const f16x8*)(ap + 256);  // lo (x2048)
                #pragma unroll
                for (int nf = 0; nf < 2; ++nf) {
                    acc0[mf][nf] = __builtin_amdgcn_mfma_f32_16x16x32_f16(a0, bh[nf], acc0[mf][nf], 0, 0, 0);
                    acc1[mf][nf] = __builtin_amdgcn_mfma_f32_16x16x32_f16(a0, bl[nf], acc1[mf][nf], 0, 0, 0);
                    acc1[mf][nf] = __builtin_amdgcn_mfma_f32_16x16x32_f16(a1, bh[nf], acc1[mf][nf], 0, 0, 0);
                }
            }
        }
        #pragma unroll
        for (int nf = 0; nf < 2; ++nf) {
            int code = (gbase + nf) * 16 + lr;
            float cnv = cn[code];
            #pragma unroll
            for (int mf = 0; mf < 4; ++mf)
                #pragma unroll
                for (int r = 0; r < 4; ++r) {
                    float dot = fmaf(acc1[mf][nf][r], (1.0f / 2048.0f), acc0[mf][nf][r]);
                    float s = fmaf(-2.0f, dot, cnv);
                    if (s < best_s[mf][r] || (s == best_s[mf][r] && code < best_i[mf][r])) {
                        best_s[mf][r] = s; best_i[mf][r] = code;
                    }
                }
        }
    }
    #pragma unroll
    for (int m = 1; m < 16; m <<= 1) {
        #pragma unroll
        for (int mf = 0; mf < 4; ++mf)
            #pragma unroll
            for (int r = 0; r < 4; ++r) {
                float os = __shfl_xor(best_s[mf][r], m, 64);
                int   oi = __shfl_xor(best_i[mf][r], m, 64);
                if (os < best_s[mf][r] || (os == best_s[mf][r] && oi < best_i[mf][r])) {
                    best_s[mf][r] = os; best_i[mf][r] = oi;
                }
            }
    }
    if (lr == 0) {
        #pragma unroll
        for (int mf = 0; mf < 4; ++mf)
            #pragma unroll
            for (int r = 0; r < 4; ++r) {
                int row = mf * 16 + hi * 4 + r;
                redS[wv][row] = best_s[mf][r];
                redI[wv][row] = best_i[mf][r];
            }
    }
    __syncthreads();
    if (tid < 64) {
        float bs = redS[0][tid]; int bi = redI[0][tid];
        for (int ww = 1; ww < 8; ++ww) {
            float s = redS[ww][tid]; int i2 = redI[ww][tid];
            if (s < bs || (s == bs && i2 < bi)) { bs = s; bi = i2; }
        }
        int rowg = row0 + tid;
        idx[rowg] = bi;
        atomicAdd(counts + bi, 1);
        int bimg = rowg >> 8, n = rowg & 255;
        __builtin_nontemporal_store(1.0f,
            oh + (size_t)bimg * (KCB * 256) + (size_t)bi * 256 + n);
        winner[tid] = bi;
    }
    __syncthreads();
    {   // exact fp32 SSE for the winners
        int row = tid >> 3, seg = tid & 7;
        int bi = winner[row];
        const float* cp = cb + (size_t)bi * 256 + seg * 32;
        const float* ep = e + (size_t)(row0 + row) * 256 + seg * 32;
        float s = 0.f;
        #pragma unroll
        for (int i = 0; i < 32; i += 4) {
            float4 a = *(const float4*)(cp + i);
            float4 b = *(const float4*)(ep + i);
            float d0 = a.x - b.x, d1 = a.y - b.y, d2 = a.z - b.z, d3 = a.w - b.w;
            s = fmaf(d0, d0, s); s = fmaf(d1, d1, s);
            s = fmaf(d2, d2, s); s = fmaf(d3, d3, s);
        }
        s += __shfl_down(s, 4, 64);
        s += __shfl_down(s, 2, 64);
        s += __shfl_down(s, 1, 64);
        if ((tid & 7) == 0) sred[row] = s;
    }
    __syncthreads();
    if (tid == 0) {
        float t = 0.f;
        for (int i = 0; i < 64; ++i) t += sred[i];
        atomicAdd(sse, t);
    }
}

// ---------------- prepack: codebook -> bf16 (for convT1) -------------------
__global__ void k_cb2bf(const float* __restrict__ cb, unsigned short* __restrict__ cbb) {
    int t = blockIdx.x * 256 + threadIdx.x;
    float4 v = *(const float4*)(cb + (size_t)t * 4);
    ushort4 o;
    o.x = f2bf(v.x); o.y = f2bf(v.y); o.z = f2bf(v.z); o.w = f2bf(v.w);
    *(ushort4*)(cbb + (size_t)t * 4) = o;
}

// ---------------- prepack: dec_w1 -> Wp[p][tap][oc][ci] bf16 ----------------
__global__ void k_packw(const float* __restrict__ w, unsigned short* __restrict__ wp) {
    int t = blockIdx.x * 256 + threadIdx.x;
    int ci = t >> 7, oc = t & 127;
    const float* src = w + ((size_t)ci * 128 + oc) * 16;
    float tv[16];
    #pragma unroll
    for (int i = 0; i < 16; i += 4) {
        float4 v = *(const float4*)(src + i);
        tv[i] = v.x; tv[i + 1] = v.y; tv[i + 2] = v.z; tv[i + 3] = v.w;
    }
    #pragma unroll
    for (int p = 0; p < 4; ++p) {
        int a = p >> 1, b2 = p & 1;
        #pragma unroll
        for (int tap = 0; tap < 4; ++tap) {
            int dy = tap >> 1, dx = tap & 1;
            float v = tv[((1 - a) + 2 * dy) * 4 + (1 - b2) + 2 * dx];
            wp[((((p * 4 + tap) * 128) + oc) << 8) + ci] = f2bf(v);
        }
    }
}

// ---------------- packw2t: dw2 (128,3,4,4) -> convt2 B-frag table bf16 -----
__global__ void k_packw2t(const float* __restrict__ w, unsigned short* __restrict__ wt) {
    int t = blockIdx.x * 256 + threadIdx.x;    // 32768
    int el = t & 7, lr = (t >> 3) & 15, hi = (t >> 7) & 3;
    int cig = (t >> 9) & 3, tp = (t >> 11) & 3, p = (t >> 13) & 3;
    int ci = cig * 32 + hi * 8 + el;
    int a = p >> 1, bb = p & 1;
    int ky0 = 1 - a, kx0 = 1 - bb;
    int wtap;
    if (tp == 0) wtap = ky0 * 4 + kx0;
    else if (tp == 1) wtap = ky0 * 4 + kx0 + 2;
    else if (tp == 2) wtap = (ky0 + 2) * 4 + kx0;
    else wtap = (ky0 + 2) * 4 + kx0 + 2;
    unsigned short v = 0;
    if (lr < 3) v = f2bf(w[((size_t)ci * 3 + lr) * 16 + wtap]);
    wt[t] = v;
}

// ---------------- convT1 via MFMA -> d1b bf16 [b][y][x][ci], relu ----------
__global__ __launch_bounds__(512) void k_convt1_mfma(const int* __restrict__ idx,
        const unsigned short* __restrict__ cbb, const unsigned short* __restrict__ wp,
        const float* __restrict__ bias, unsigned short* __restrict__ d1b) {
    __shared__ unsigned short As[257 * 72];
    __shared__ unsigned short Bs[128 * 72];
    __shared__ int sidx[256];
    const int tid = threadIdx.x;
    const int b  = blockIdx.y;
    const int p  = blockIdx.x;
    const int a  = p >> 1, bb2 = p & 1;
    if (tid < 256) sidx[tid] = idx[b * 256 + tid] * 256;
    if (tid < 72)  As[256 * 72 + tid] = 0;
    const int lane = tid & 63;
    const int w    = tid >> 6;
    const int wm = w >> 2, wn = w & 3;
    const int lr = lane & 15, hi = lane >> 4;
    const int koff = hi * 8;
    f32x4 acc[8][2];
    #pragma unroll
    for (int i = 0; i < 8; ++i)
        #pragma unroll
        for (int j = 0; j < 2; ++j) acc[i][j] = (f32x4){0.f, 0.f, 0.f, 0.f};

    for (int c0 = 0; c0 < 256; c0 += 64) {
        for (int tap = 0; tap < 4; ++tap) {
            __syncthreads();
            if (tap == 0) {
                int row = tid >> 1, half = tid & 1;
                const uint4* src = (const uint4*)(cbb + sidx[row] + c0 + half * 32);
                uint4 v0 = src[0], v1 = src[1], v2 = src[2], v3 = src[3];
                uint4* dst = (uint4*)(As + row * 72 + half * 32);
                dst[0] = v0; dst[1] = v1; dst[2] = v2; dst[3] = v3;
            }
            {
                int oc = tid >> 2, q = tid & 3;
                const uint4* src = (const uint4*)(wp + (((p * 4 + tap) * 128 + oc) << 8) + c0 + q * 16);
                uint4 v0 = src[0], v1 = src[1];
                uint4* dst = (uint4*)(Bs + oc * 72 + q * 16);
                dst[0] = v0; dst[1] = v1;
            }
            __syncthreads();
            const int dy = tap >> 1, dx = tap & 1;
            const int xo = lr + bb2 - dx;
            const bool xv = (xo >= 0) && (xo < 16);
            #pragma unroll
            for (int kk = 0; kk < 2; ++kk) {
                bf16x8 aF[8];
                #pragma unroll
                for (int i = 0; i < 8; ++i) {
                    int typ = wm * 8 + i + a - dy;
                    int row = (xv && typ >= 0 && typ < 16) ? typ * 16 + xo : 256;
                    aF[i] = *(const bf16x8*)(As + row * 72 + kk * 32 + koff);
                }
                #pragma unroll
                for (int j = 0; j < 2; ++j) {
                    bf16x8 bF = *(const bf16x8*)(Bs + ((wn * 2 + j) * 16 + lr) * 72 + kk * 32 + koff);
                    #pragma unroll
                    for (int i = 0; i < 8; ++i)
                        acc[i][j] = __builtin_amdgcn_mfma_f32_16x16x32_bf16(aF[i], bF, acc[i][j], 0, 0, 0);
                }
            }
        }
    }
    #pragma unroll
    for (int j = 0; j < 2; ++j) {
        int oc = (wn * 2 + j) * 16 + lr;
        float bv = bias[oc];
        #pragma unroll
        for (int i = 0; i < 8; ++i) {
            int mt = wm * 8 + i;
            int oy = 2 * mt + a;
            #pragma unroll
            for (int r = 0; r < 4; ++r) {
                int ox = bb2 + 2 * (hi * 4 + r);
                float v = acc[i][j][r] + bv;
                v = v > 0.f ? v : 0.f;
                d1b[(((size_t)b * 32 + oy) * 32 + ox) * 128 + oc] = f2bf(v);
            }
        }
    }
}

// ---------------- convT2 via MFMA: d1b -> x_hat ----------------------------
__global__ __launch_bounds__(512) void k_convt2_mfma(const unsigned short* __restrict__ d1b,
        const unsigned short* __restrict__ wt, const float* __restrict__ bias,
        float* __restrict__ xhat) {
    __shared__ __attribute__((aligned(16))) unsigned short sd[18 * 34 * 32]; // [l][xx][ci32]
    const int tid = threadIdx.x;
    const int b = blockIdx.y;
    const int p = blockIdx.x >> 1, yh = blockIdx.x & 1;
    const int a = p >> 1, bb = p & 1;
    const int lane = tid & 63, wv = tid >> 6;
    const int lr = lane & 15, hi = lane >> 4;

    f32x4 acc[4];
    #pragma unroll
    for (int i = 0; i < 4; ++i) acc[i] = (f32x4){0.f, 0.f, 0.f, 0.f};

    for (int cig = 0; cig < 4; ++cig) {
        __syncthreads();
        for (int q4 = tid; q4 < 2448; q4 += 512) {       // 18*34*4 uint4
            int l = q4 / 136, rem = q4 % 136, xx = rem >> 2, q = rem & 3;
            int iy = yh * 16 - 1 + l, ixx = xx - 1;
            uint4* dst = (uint4*)(sd + (l * 34 + xx) * 32 + q * 8);
            if (iy >= 0 && iy < 32 && ixx >= 0 && ixx < 32)
                *dst = *(const uint4*)(d1b + (((size_t)b * 32 + iy) * 32 + ixx) * 128 + cig * 32 + q * 8);
            else
                *dst = (uint4){0u, 0u, 0u, 0u};
        }
        __syncthreads();
        #pragma unroll
        for (int tp = 0; tp < 4; ++tp) {
            const unsigned short* bp = wt + ((((p * 4 + tp) * 4 + cig) * 4 + hi) * 16 + lr) * 8;
            bf16x8 bF = *(const bf16x8*)bp;
            #pragma unroll
            for (int mf = 0; mf < 4; ++mf) {
                int pos = wv * 64 + mf * 16 + lr;
                int myl = pos >> 5, mx = pos & 31;
                int l = myl + a + (tp < 2 ? 1 : 0);
                int xx = mx + bb + ((tp & 1) ? 0 : 1);
                bf16x8 aF = *(const bf16x8*)(sd + (l * 34 + xx) * 32 + hi * 8);
                acc[mf] = __builtin_amdgcn_mfma_f32_16x16x32_bf16(aF, bF, acc[mf], 0, 0, 0);
            }
        }
    }
    if (lr < 3) {
        float bv = bias[lr];
        #pragma unroll
        for (int mf = 0; mf < 4; ++mf) {
            #pragma unroll
            for (int r = 0; r < 4; ++r) {
                int pos = wv * 64 + mf * 16 + hi * 4 + r;
                int oy = 2 * (yh * 16 + (pos >> 5)) + a;
                int ox = 2 * (pos & 31) + bb;
                xhat[(((size_t)b * 3 + lr) * 64 + oy) * 64 + ox] = acc[mf][r] + bv;
            }
        }
    }
}

// ---------------- finalize: loss + perplexity ------------------------------
__global__ void k_final(const int* __restrict__ counts, const float* __restrict__ sse,
                        float* __restrict__ out_loss, float* __restrict__ out_perp) {
    __shared__ float red[256];
    int tid = threadIdx.x;
    float s = 0.f;
    for (int k = tid; k < 1024; k += 256) {
        float p = (float)counts[k] * (1.f / 32768.f);
        s += p * logf(p + 1e-10f);
    }
    red[tid] = s;
    __syncthreads();
    for (int st = 128; st > 0; st >>= 1) {
        if (tid < st) red[tid] += red[tid + st];
        __syncthreads();
    }
    if (tid == 0) {
        *out_perp = expf(-red[0]);
        *out_loss = 0.25f * (*sse) / 8388608.0f;
    }
}

extern "C" void kernel_launch(void* const* d_in, const int* in_sizes, int n_in,
                              void* d_out, int out_size, void* d_ws, size_t ws_size,
                              hipStream_t stream) {
    const float* x   = (const float*)d_in[0];
    const float* ew1 = (const float*)d_in[1];
    const float* eb1 = (const float*)d_in[2];
    const float* ew2 = (const float*)d_in[3];
    const float* eb2 = (const float*)d_in[4];
    const float* dw1 = (const float*)d_in[5];
    const float* db1 = (const float*)d_in[6];
    const float* dw2 = (const float*)d_in[7];
    const float* db2 = (const float*)d_in[8];
    const float* cb  = (const float*)d_in[9];

    float* out  = (float*)d_out;
    float* xhat = out;                       // 128*3*64*64 = 1572864
    float* loss = out + 1572864;
    float* perp = out + 1572865;
    float* oh   = out + 1572866;             // 128*1024*256 = 33554432

    char* ws = (char*)d_ws;
    unsigned short* hA = (unsigned short*)ws;                 // 64 MB (dead after conv2)
    float* e      = (float*)(ws + (size_t)64 * 1024 * 1024);  // 32 MB (dead after vq)
    int*   idx    = (int*)(ws + (size_t)96 * 1024 * 1024);    // 128 KB
    int*   counts = idx + NLAT;                               // 4 KB
    float* sse    = (float*)(counts + KCB);                   // 4 B
    float* cn     = sse + 1;                                  // 4 KB
    unsigned short* cbp = (unsigned short*)ws;                // 1 MB (after conv2)
    unsigned short* d1b = (unsigned short*)ws;                // 32 MB (after vq; clobbers cbp)
    unsigned short* cbb = (unsigned short*)e;                 // 512 KB (after vq)
    unsigned short* wpk = (unsigned short*)(ws + (size_t)65 * 1024 * 1024);  // 1 MB (after vq)
    unsigned short* wt  = (unsigned short*)(ws + (size_t)67 * 1024 * 1024);  // 64 KB (after vq)
    unsigned short* wpf = (unsigned short*)(((uintptr_t)oh + 15) & ~(uintptr_t)15);  // 2 MB in oh region

    hipMemsetAsync(counts, 0, KCB * 4 + 4, stream);

    k_cnorm<<<4, 256, 0, stream>>>(cb, cn);
    k_packwf<<<128, 256, 0, stream>>>(ew2, wpf);               // dirties oh[0:2MB]
    k_conv1<<<dim3(8, 128), 256, 0, stream>>>(x, ew1, eb1, hA);
    k_zero_oh<<<2048, 256, 0, stream>>>(oh + 524304, (33554432 - 524304) / 4);  // beyond wpf slice
    k_conv2_mfma<<<dim3(4, 128), 512, 0, stream>>>(hA, wpf, eb2, e);
    k_zero_oh<<<64, 256, 0, stream>>>(oh, 524304 / 4);          // re-zero wpf slice
    k_packcbp<<<1024, 256, 0, stream>>>(cb, cbp);              // hA region now dead
    k_vq_mfma<<<512, 512, 0, stream>>>(e, cbp, cn, cb, idx, counts, sse, oh);
    k_cb2bf<<<256, 256, 0, stream>>>(cb, cbb);
    k_packw<<<128, 256, 0, stream>>>(dw1, wpk);
    k_packw2t<<<128, 256, 0, stream>>>(dw2, wt);
    k_convt1_mfma<<<dim3(4, 128), 512, 0, stream>>>(idx, cbb, wpk, db1, d1b);  // clobbers cbp (dead)
    k_convt2_mfma<<<dim3(8, 128), 512, 0, stream>>>(d1b, wt, db2, xhat);
    k_final<<<1, 256, 0, stream>>>(counts, sse, loss, perp);
}

// Round 21
// 579.962 us; speedup vs baseline: 1.5200x; 1.0056x over previous
//
#include <hip/hip_runtime.h>
#include <stdint.h>

#define NB   128
#define CIN  3
#define HID  128
#define DEM  256
#define KCB  1024
#define NLAT 32768   // NB*16*16

typedef __bf16 bf16x8 __attribute__((ext_vector_type(8)));
typedef _Float16 f16x8 __attribute__((ext_vector_type(8)));
typedef float  f32x4  __attribute__((ext_vector_type(4)));

__device__ inline unsigned short f2bf(float f) {
    unsigned u = __builtin_bit_cast(unsigned, f);
    u = (u + 0x7fff + ((u >> 16) & 1)) >> 16;
    return (unsigned short)u;
}

// ---------------- zero-fill oh with non-temporal stores --------------------
__global__ __launch_bounds__(256) void k_zero_oh(float* __restrict__ oh, int n4) {
    int t = blockIdx.x * 256 + threadIdx.x;
    f32x4 z = {0.f, 0.f, 0.f, 0.f};
    for (int i = t; i < n4; i += 256 * 2048)
        __builtin_nontemporal_store(z, (f32x4*)(oh + (size_t)i * 4));
}

// ---------------- conv1: x(128,3,64,64) -> hA fp16 hi/lo records, relu -----
__global__ __launch_bounds__(256) void k_conv1(const float* __restrict__ x,
        const float* __restrict__ w, const float* __restrict__ bias,
        unsigned short* __restrict__ hA) {
    __shared__ float sx[3][66][66];
    const int b = blockIdx.y;
    const int ocg = blockIdx.x;
    const int oc0 = ocg * 16;
    const int tid = threadIdx.x;
    for (int i = tid; i < 3 * 66 * 66; i += 256) ((float*)sx)[i] = 0.f;
    __syncthreads();
    const float* xb = x + (size_t)b * (3 * 64 * 64);
    for (int i = tid; i < 3 * 64 * 64; i += 256) {
        int ic = i >> 12; int rem = i & 4095; int y = rem >> 6; int xx = rem & 63;
        sx[ic][y + 1][xx + 1] = xb[i];
    }
    __syncthreads();
    for (int j = 0; j < 4; ++j) {
        int pos = tid + j * 256;
        int oy = pos >> 5, ox = pos & 31;
        float acc[16];
        #pragma unroll
        for (int i = 0; i < 16; ++i) acc[i] = 0.f;
        int iy0 = 2 * oy;
        int ix0 = 2 * ox;
        for (int ic = 0; ic < 3; ++ic) {
            float p[16];
            #pragma unroll
            for (int ky = 0; ky < 4; ++ky)
                #pragma unroll
                for (int kx = 0; kx < 4; ++kx)
                    p[ky * 4 + kx] = sx[ic][iy0 + ky][ix0 + kx];
            #pragma unroll
            for (int oc = 0; oc < 16; ++oc) {
                const float* wp = w + ((oc0 + oc) * 3 + ic) * 16;
                float a = acc[oc];
                #pragma unroll
                for (int t = 0; t < 16; ++t) a = fmaf(p[t], wp[t], a);
                acc[oc] = a;
            }
        }
        unsigned short rec[32];
        #pragma unroll
        for (int oc = 0; oc < 16; ++oc) {
            float v = acc[oc] + bias[oc0 + oc];
            v = v > 0.f ? v : 0.f;
            _Float16 hh = (_Float16)v;
            float hf = (float)hh;
            _Float16 ll = (_Float16)((v - hf) * 2048.0f);
            rec[oc] = __builtin_bit_cast(unsigned short, hh);
            rec[16 + oc] = __builtin_bit_cast(unsigned short, ll);
        }
        uint4* dst = (uint4*)(hA + ((size_t)(b * 8 + ocg) * 1024 + pos) * 32);
        uint4* r4 = (uint4*)rec;
        dst[0] = r4[0]; dst[1] = r4[1]; dst[2] = r4[2]; dst[3] = r4[3];
    }
}

// ---------------- packwf: ew2 OIHW -> fragment-ordered fp16 hi/lo ----------
__global__ void k_packwf(const float* __restrict__ w, unsigned short* __restrict__ wpf) {
    int t = blockIdx.x * 256 + threadIdx.x;   // 32768: (oc 256, c0 8, ci 16)
    int oc = t >> 7, rest = t & 127;
    int c0 = rest >> 4, ci = rest & 15;
    const float* src = w + ((size_t)(oc * 128 + c0 * 16 + ci)) * 16;
    float tv[16];
    #pragma unroll
    for (int i = 0; i < 16; i += 4) {
        float4 v = *(const float4*)(src + i);
        tv[i] = v.x; tv[i + 1] = v.y; tv[i + 2] = v.z; tv[i + 3] = v.w;
    }
    int g = oc >> 4, lr = oc & 15;
    #pragma unroll
    for (int ks = 0; ks < 8; ++ks) {
        int ky = ks >> 1, kxp = ks & 1;
        #pragma unroll
        for (int kxh = 0; kxh < 2; ++kxh) {
            float v = tv[ky * 4 + 2 * kxp + kxh];
            _Float16 hh = (_Float16)v;
            float hf = (float)hh;
            _Float16 ll = (_Float16)((v - hf) * 2048.0f);
            int d = kxh * 16 + ci;
            int hi = d >> 3, el = d & 7;
            size_t base = ((((size_t)(c0 * 8 + ks) * 16 + g) * 2 + 0) * 4 + hi) * 128 + lr * 8 + el;
            wpf[base]       = __builtin_bit_cast(unsigned short, hh);
            wpf[base + 512] = __builtin_bit_cast(unsigned short, ll);   // plane 1
        }
    }
}

// ---------------- conv2 via split-fp16 MFMA: M=128, B regs from global -----
__global__ __launch_bounds__(512) void k_conv2_mfma(const unsigned short* __restrict__ hA,
        const unsigned short* __restrict__ wpf, const float* __restrict__ bias,
        float* __restrict__ e) {
    __shared__ __attribute__((aligned(16))) unsigned short As[577 * 40]; // slot: [16 hi][16 lo][8 pad]
    const int tid = threadIdx.x;
    const int b = blockIdx.y;
    const int ocg = blockIdx.x >> 1, yh = blockIdx.x & 1;
    const int lane = tid & 63, wv = tid >> 6;
    const int wm = wv >> 2, wn = wv & 3;
    const int lr = lane & 15, hi = lane >> 4;

    if (tid < 40) As[576 * 40 + tid] = 0;   // zero slot for x-halo

    f32x4 acc0[4][2], acc1[4][2];
    #pragma unroll
    for (int i = 0; i < 4; ++i)
        #pragma unroll
        for (int j = 0; j < 2; ++j) {
            acc0[i][j] = (f32x4){0.f, 0.f, 0.f, 0.f};
            acc1[i][j] = (f32x4){0.f, 0.f, 0.f, 0.f};
        }

    for (int c0 = 0; c0 < 8; ++c0) {
        __syncthreads();
        {   // stage A: 18 rows x 32 ix x 32 us = 2304 uint4 (pure copy)
            const size_t cbase = (size_t)(b * 8 + c0) * 1024;
            for (int p = tid; p < 2304; p += 512) {
                int l = p >> 7, rem = p & 127;
                int ixs = rem >> 2, q = rem & 3;
                int iy = yh * 16 - 1 + l;
                uint4* dst = (uint4*)(As + (l * 32 + (ixs & 1) * 16 + (ixs >> 1)) * 40 + q * 8);
                if (iy >= 0 && iy < 32)
                    *dst = *(const uint4*)(hA + (cbase + iy * 32 + ixs) * 32 + q * 8);
                else
                    *dst = (uint4){0u, 0u, 0u, 0u};
            }
        }
        __syncthreads();
        #pragma unroll
        for (int ks = 0; ks < 8; ++ks) {
            const int ky = ks >> 1, kxp = ks & 1;
            f16x8 bh[2], bl[2];
            #pragma unroll
            for (int nf = 0; nf < 2; ++nf) {
                const unsigned short* bp = wpf
                    + ((((size_t)(c0 * 8 + ks) * 16 + (ocg * 8 + wn * 2 + nf)) * 2 + 0) * 4 + hi) * 128 + lr * 8;
                bh[nf] = *(const f16x8*)bp;
                bl[nf] = *(const f16x8*)(bp + 512);
            }
            const int o = 2 * kxp - 1 + (hi >> 1);
            const int ix = 2 * lr + o;
            const bool xv = (ix >= 0) && (ix < 32);
            const int sbase = (o & 1) * 16 + (ix >> 1);
            #pragma unroll
            for (int mf = 0; mf < 4; ++mf) {
                int l = 2 * (wm * 4 + mf) + ky;
                int slot = xv ? (l * 32 + sbase) : 576;
                const unsigned short* ap = As + slot * 40 + (hi & 1) * 8;
                f16x8 a0 = *(const f16x8*)ap;          // hi
                f16x8 a1 = *(const f16x8*)(ap + 16);   // lo (x2048)
                #pragma unroll
                for (int nf = 0; nf < 2; ++nf) {
                    acc0[mf][nf] = __builtin_amdgcn_mfma_f32_16x16x32_f16(a0, bh[nf], acc0[mf][nf], 0, 0, 0);
                    acc1[mf][nf] = __builtin_amdgcn_mfma_f32_16x16x32_f16(a0, bl[nf], acc1[mf][nf], 0, 0, 0);
                    acc1[mf][nf] = __builtin_amdgcn_mfma_f32_16x16x32_f16(a1, bh[nf], acc1[mf][nf], 0, 0, 0);
                }
            }
        }
    }
    #pragma unroll
    for (int mf = 0; mf < 4; ++mf) {
        int oy = yh * 8 + wm * 4 + mf;
        #pragma unroll
        for (int nf = 0; nf < 2; ++nf) {
            int oc = ocg * 128 + wn * 32 + nf * 16 + lr;
            float bv = bias[oc];
            #pragma unroll
            for (int r = 0; r < 4; ++r) {
                int ox = hi * 4 + r;
                size_t erow = (size_t)b * 256 + (size_t)oy * 16 + ox;
                e[erow * 256 + oc] = acc0[mf][nf][r] + acc1[mf][nf][r] * (1.0f / 2048.0f) + bv;
            }
        }
    }
}

// ---------------- code norms ----------------
__global__ void k_cnorm(const float* __restrict__ cb, float* __restrict__ cn) {
    int k = blockIdx.x * 256 + threadIdx.x;
    const float* cp = cb + (size_t)k * 256;
    float s = 0.f;
    #pragma unroll 8
    for (int d = 0; d < 256; d += 4) {
        float4 v = *(const float4*)(cp + d);
        s = fmaf(v.x, v.x, s); s = fmaf(v.y, v.y, s);
        s = fmaf(v.z, v.z, s); s = fmaf(v.w, v.w, s);
    }
    cn[k] = s;
}

// ---------------- codebook -> MFMA-fragment-ordered fp16 hi/lo -------------
__global__ void k_packcbp(const float* __restrict__ cb, unsigned short* __restrict__ cbp) {
    int t = blockIdx.x * 256 + threadIdx.x;   // 262144: (code, dim)
    int c = t >> 8, d = t & 255;
    float v = cb[(size_t)c * 256 + d];
    _Float16 hh = (_Float16)v;
    float hf = (float)hh;
    _Float16 ll = (_Float16)((v - hf) * 2048.0f);
    int g = c >> 4, lr = c & 15;
    int kq = d >> 5, rem = d & 31, hi = rem >> 3, el = rem & 7;
    size_t b0 = ((((size_t)(g * 8 + kq) * 2 + 0) * 4 + hi) * 16 + lr) * 8 + el;
    size_t b1 = ((((size_t)(g * 8 + kq) * 2 + 1) * 4 + hi) * 16 + lr) * 8 + el;
    cbp[b0] = __builtin_bit_cast(unsigned short, hh);
    cbp[b1] = __builtin_bit_cast(unsigned short, ll);
}

// ---------------- VQ via split-fp16 MFMA (r11 form — empirical optimum) ----
__global__ __launch_bounds__(512) void k_vq_mfma(const float* __restrict__ e,
        const unsigned short* __restrict__ cbp, const float* __restrict__ cn,
        const float* __restrict__ cb,
        int* __restrict__ idx, int* __restrict__ counts, float* __restrict__ sse,
        float* __restrict__ oh) {
    __shared__ __attribute__((aligned(16))) unsigned short As[64 * 520]; // [256 hi][256 lo][8 pad]
    __shared__ float redS[8][64];
    __shared__ int   redI[8][64];
    __shared__ int   winner[64];
    __shared__ float sred[64];
    const int tid = threadIdx.x;
    const int lane = tid & 63;
    const int wv = tid >> 6;
    const int lr = lane & 15, hi = lane >> 4;
    const int row0 = blockIdx.x * 64;

    {   // stage A once: 64 rows x 256 k, fp32 -> fp16 hi/lo
        int row = tid >> 3, seg = tid & 7;
        const float* src = e + (size_t)(row0 + row) * 256 + seg * 32;
        unsigned short hb[32], lb[32];
        #pragma unroll
        for (int i = 0; i < 32; i += 4) {
            float4 v = *(const float4*)(src + i);
            float vv[4] = {v.x, v.y, v.z, v.w};
            #pragma unroll
            for (int q = 0; q < 4; ++q) {
                _Float16 hh = (_Float16)vv[q];
                float hf = (float)hh;
                _Float16 ll = (_Float16)((vv[q] - hf) * 2048.0f);
                hb[i + q] = __builtin_bit_cast(unsigned short, hh);
                lb[i + q] = __builtin_bit_cast(unsigned short, ll);
            }
        }
        uint4* dh = (uint4*)(As + row * 520 + seg * 32);
        uint4* dl = (uint4*)(As + row * 520 + 256 + seg * 32);
        #pragma unroll
        for (int u = 0; u < 4; ++u) { dh[u] = ((uint4*)hb)[u]; dl[u] = ((uint4*)lb)[u]; }
    }
    __syncthreads();

    float best_s[4][4];
    int   best_i[4][4];
    #pragma unroll
    for (int a = 0; a < 4; ++a)
        #pragma unroll
        for (int r = 0; r < 4; ++r) { best_s[a][r] = 3.4e38f; best_i[a][r] = 0; }

    for (int ncg = 0; ncg < 4; ++ncg) {
        f32x4 acc0[4][2], acc1[4][2];
        #pragma unroll
        for (int i = 0; i < 4; ++i)
            #pragma unroll
            for (int j = 0; j < 2; ++j) {
                acc0[i][j] = (f32x4){0.f, 0.f, 0.f, 0.f};
                acc1[i][j] = (f32x4){0.f, 0.f, 0.f, 0.f};
            }
        const int gbase = ncg * 16 + wv * 2;     // fragment group of 16 codes
        #pragma unroll
        for (int kq = 0; kq < 8; ++kq) {
            f16x8 bh[2], bl[2];
            #pragma unroll
            for (int nf = 0; nf < 2; ++nf) {
                const unsigned short* bp = cbp
                    + (((size_t)((gbase + nf) * 8 + kq) * 2 + 0) * 4 + hi) * 128 + lr * 8;
                bh[nf] = *(const f16x8*)bp;
                bl[nf] = *(const f16x8*)(bp + 512);
            }
            #pragma unroll
            for (int mf = 0; mf < 4; ++mf) {
                const unsigned short* ap = As + (mf * 16 + lr) * 520 + kq * 32 + hi * 8;
                f16x8 a0 = *(const f16x8*)ap;          // hi
                f16x8 a1 = *(const f16x8*)(ap + 256);  // lo (x2048)
                #pragma unroll
                for (int nf = 0; nf < 2; ++nf) {
                    acc0[mf][nf] = __builtin_amdgcn_mfma_f32_16x16x32_f16(a0, bh[nf], acc0[mf][nf], 0, 0, 0);
                    acc1[mf][nf] = __builtin_amdgcn_mfma_f32_16x16x32_f16(a0, bl[nf], acc1[mf][nf], 0, 0, 0);
                    acc1[mf][nf] = __builtin_amdgcn_mfma_f32_16x16x32_f16(a1, bh[nf], acc1[mf][nf], 0, 0, 0);
                }
            }
        }
        #pragma unroll
        for (int nf = 0; nf < 2; ++nf) {
            int code = (gbase + nf) * 16 + lr;
            float cnv = cn[code];
            #pragma unroll
            for (int mf = 0; mf < 4; ++mf)
                #pragma unroll
                for (int r = 0; r < 4; ++r) {
                    float dot = fmaf(acc1[mf][nf][r], (1.0f / 2048.0f), acc0[mf][nf][r]);
                    float s = fmaf(-2.0f, dot, cnv);
                    if (s < best_s[mf][r] || (s == best_s[mf][r] && code < best_i[mf][r])) {
                        best_s[mf][r] = s; best_i[mf][r] = code;
                    }
                }
        }
    }
    #pragma unroll
    for (int m = 1; m < 16; m <<= 1) {
        #pragma unroll
        for (int mf = 0; mf < 4; ++mf)
            #pragma unroll
            for (int r = 0; r < 4; ++r) {
                float os = __shfl_xor(best_s[mf][r], m, 64);
                int   oi = __shfl_xor(best_i[mf][r], m, 64);
                if (os < best_s[mf][r] || (os == best_s[mf][r] && oi < best_i[mf][r])) {
                    best_s[mf][r] = os; best_i[mf][r] = oi;
                }
            }
    }
    if (lr == 0) {
        #pragma unroll
        for (int mf = 0; mf < 4; ++mf)
            #pragma unroll
            for (int r = 0; r < 4; ++r) {
                int row = mf * 16 + hi * 4 + r;
                redS[wv][row] = best_s[mf][r];
                redI[wv][row] = best_i[mf][r];
            }
    }
    __syncthreads();
    if (tid < 64) {
        float bs = redS[0][tid]; int bi = redI[0][tid];
        for (int ww = 1; ww < 8; ++ww) {
            float s = redS[ww][tid]; int i2 = redI[ww][tid];
            if (s < bs || (s == bs && i2 < bi)) { bs = s; bi = i2; }
        }
        int rowg = row0 + tid;
        idx[rowg] = bi;
        atomicAdd(counts + bi, 1);
        int bimg = rowg >> 8, n = rowg & 255;
        __builtin_nontemporal_store(1.0f,
            oh + (size_t)bimg * (KCB * 256) + (size_t)bi * 256 + n);
        winner[tid] = bi;
    }
    __syncthreads();
    {   // exact fp32 SSE for the winners
        int row = tid >> 3, seg = tid & 7;
        int bi = winner[row];
        const float* cp = cb + (size_t)bi * 256 + seg * 32;
        const float* ep = e + (size_t)(row0 + row) * 256 + seg * 32;
        float s = 0.f;
        #pragma unroll
        for (int i = 0; i < 32; i += 4) {
            float4 a = *(const float4*)(cp + i);
            float4 b = *(const float4*)(ep + i);
            float d0 = a.x - b.x, d1 = a.y - b.y, d2 = a.z - b.z, d3 = a.w - b.w;
            s = fmaf(d0, d0, s); s = fmaf(d1, d1, s);
            s = fmaf(d2, d2, s); s = fmaf(d3, d3, s);
        }
        s += __shfl_down(s, 4, 64);
        s += __shfl_down(s, 2, 64);
        s += __shfl_down(s, 1, 64);
        if ((tid & 7) == 0) sred[row] = s;
    }
    __syncthreads();
    if (tid == 0) {
        float t = 0.f;
        for (int i = 0; i < 64; ++i) t += sred[i];
        atomicAdd(sse, t);
    }
}

// ---------------- prepack: codebook -> bf16 (for convT1) -------------------
__global__ void k_cb2bf(const float* __restrict__ cb, unsigned short* __restrict__ cbb) {
    int t = blockIdx.x * 256 + threadIdx.x;
    float4 v = *(const float4*)(cb + (size_t)t * 4);
    ushort4 o;
    o.x = f2bf(v.x); o.y = f2bf(v.y); o.z = f2bf(v.z); o.w = f2bf(v.w);
    *(ushort4*)(cbb + (size_t)t * 4) = o;
}

// ---------------- prepack: dec_w1 -> Wp[p][tap][oc][ci] bf16 ----------------
__global__ void k_packw(const float* __restrict__ w, unsigned short* __restrict__ wp) {
    int t = blockIdx.x * 256 + threadIdx.x;
    int ci = t >> 7, oc = t & 127;
    const float* src = w + ((size_t)ci * 128 + oc) * 16;
    float tv[16];
    #pragma unroll
    for (int i = 0; i < 16; i += 4) {
        float4 v = *(const float4*)(src + i);
        tv[i] = v.x; tv[i + 1] = v.y; tv[i + 2] = v.z; tv[i + 3] = v.w;
    }
    #pragma unroll
    for (int p = 0; p < 4; ++p) {
        int a = p >> 1, b2 = p & 1;
        #pragma unroll
        for (int tap = 0; tap < 4; ++tap) {
            int dy = tap >> 1, dx = tap & 1;
            float v = tv[((1 - a) + 2 * dy) * 4 + (1 - b2) + 2 * dx];
            wp[((((p * 4 + tap) * 128) + oc) << 8) + ci] = f2bf(v);
        }
    }
}

// ---------------- packw2t: dw2 (128,3,4,4) -> convt2 B-frag table bf16 -----
__global__ void k_packw2t(const float* __restrict__ w, unsigned short* __restrict__ wt) {
    int t = blockIdx.x * 256 + threadIdx.x;    // 32768
    int el = t & 7, lr = (t >> 3) & 15, hi = (t >> 7) & 3;
    int cig = (t >> 9) & 3, tp = (t >> 11) & 3, p = (t >> 13) & 3;
    int ci = cig * 32 + hi * 8 + el;
    int a = p >> 1, bb = p & 1;
    int ky0 = 1 - a, kx0 = 1 - bb;
    int wtap;
    if (tp == 0) wtap = ky0 * 4 + kx0;
    else if (tp == 1) wtap = ky0 * 4 + kx0 + 2;
    else if (tp == 2) wtap = (ky0 + 2) * 4 + kx0;
    else wtap = (ky0 + 2) * 4 + kx0 + 2;
    unsigned short v = 0;
    if (lr < 3) v = f2bf(w[((size_t)ci * 3 + lr) * 16 + wtap]);
    wt[t] = v;
}

// ---------------- convT1 via MFMA -> d1b bf16 [b][y][x][ci], relu ----------
__global__ __launch_bounds__(512) void k_convt1_mfma(const int* __restrict__ idx,
        const unsigned short* __restrict__ cbb, const unsigned short* __restrict__ wp,
        const float* __restrict__ bias, unsigned short* __restrict__ d1b) {
    __shared__ unsigned short As[257 * 72];
    __shared__ unsigned short Bs[128 * 72];
    __shared__ int sidx[256];
    const int tid = threadIdx.x;
    const int b  = blockIdx.y;
    const int p  = blockIdx.x;
    const int a  = p >> 1, bb2 = p & 1;
    if (tid < 256) sidx[tid] = idx[b * 256 + tid] * 256;
    if (tid < 72)  As[256 * 72 + tid] = 0;
    const int lane = tid & 63;
    const int w    = tid >> 6;
    const int wm = w >> 2, wn = w & 3;
    const int lr = lane & 15, hi = lane >> 4;
    const int koff = hi * 8;
    f32x4 acc[8][2];
    #pragma unroll
    for (int i = 0; i < 8; ++i)
        #pragma unroll
        for (int j = 0; j < 2; ++j) acc[i][j] = (f32x4){0.f, 0.f, 0.f, 0.f};

    for (int c0 = 0; c0 < 256; c0 += 64) {
        for (int tap = 0; tap < 4; ++tap) {
            __syncthreads();
            if (tap == 0) {
                int row = tid >> 1, half = tid & 1;
                const uint4* src = (const uint4*)(cbb + sidx[row] + c0 + half * 32);
                uint4 v0 = src[0], v1 = src[1], v2 = src[2], v3 = src[3];
                uint4* dst = (uint4*)(As + row * 72 + half * 32);
                dst[0] = v0; dst[1] = v1; dst[2] = v2; dst[3] = v3;
            }
            {
                int oc = tid >> 2, q = tid & 3;
                const uint4* src = (const uint4*)(wp + (((p * 4 + tap) * 128 + oc) << 8) + c0 + q * 16);
                uint4 v0 = src[0], v1 = src[1];
                uint4* dst = (uint4*)(Bs + oc * 72 + q * 16);
                dst[0] = v0; dst[1] = v1;
            }
            __syncthreads();
            const int dy = tap >> 1, dx = tap & 1;
            const int xo = lr + bb2 - dx;
            const bool xv = (xo >= 0) && (xo < 16);
            #pragma unroll
            for (int kk = 0; kk < 2; ++kk) {
                bf16x8 aF[8];
                #pragma unroll
                for (int i = 0; i < 8; ++i) {
                    int typ = wm * 8 + i + a - dy;
                    int row = (xv && typ >= 0 && typ < 16) ? typ * 16 + xo : 256;
                    aF[i] = *(const bf16x8*)(As + row * 72 + kk * 32 + koff);
                }
                #pragma unroll
                for (int j = 0; j < 2; ++j) {
                    bf16x8 bF = *(const bf16x8*)(Bs + ((wn * 2 + j) * 16 + lr) * 72 + kk * 32 + koff);
                    #pragma unroll
                    for (int i = 0; i < 8; ++i)
                        acc[i][j] = __builtin_amdgcn_mfma_f32_16x16x32_bf16(aF[i], bF, acc[i][j], 0, 0, 0);
                }
            }
        }
    }
    #pragma unroll
    for (int j = 0; j < 2; ++j) {
        int oc = (wn * 2 + j) * 16 + lr;
        float bv = bias[oc];
        #pragma unroll
        for (int i = 0; i < 8; ++i) {
            int mt = wm * 8 + i;
            int oy = 2 * mt + a;
            #pragma unroll
            for (int r = 0; r < 4; ++r) {
                int ox = bb2 + 2 * (hi * 4 + r);
                float v = acc[i][j][r] + bv;
                v = v > 0.f ? v : 0.f;
                d1b[(((size_t)b * 32 + oy) * 32 + ox) * 128 + oc] = f2bf(v);
            }
        }
    }
}

// ---------------- convT2 via MFMA: d1b -> x_hat ----------------------------
__global__ __launch_bounds__(512) void k_convt2_mfma(const unsigned short* __restrict__ d1b,
        const unsigned short* __restrict__ wt, const float* __restrict__ bias,
        float* __restrict__ xhat) {
    __shared__ __attribute__((aligned(16))) unsigned short sd[18 * 34 * 32]; // [l][xx][ci32]
    const int tid = threadIdx.x;
    const int b = blockIdx.y;
    const int p = blockIdx.x >> 1, yh = blockIdx.x & 1;
    const int a = p >> 1, bb = p & 1;
    const int lane = tid & 63, wv = tid >> 6;
    const int lr = lane & 15, hi = lane >> 4;

    f32x4 acc[4];
    #pragma unroll
    for (int i = 0; i < 4; ++i) acc[i] = (f32x4){0.f, 0.f, 0.f, 0.f};

    for (int cig = 0; cig < 4; ++cig) {
        __syncthreads();
        for (int q4 = tid; q4 < 2448; q4 += 512) {       // 18*34*4 uint4
            int l = q4 / 136, rem = q4 % 136, xx = rem >> 2, q = rem & 3;
            int iy = yh * 16 - 1 + l, ixx = xx - 1;
            uint4* dst = (uint4*)(sd + (l * 34 + xx) * 32 + q * 8);
            if (iy >= 0 && iy < 32 && ixx >= 0 && ixx < 32)
                *dst = *(const uint4*)(d1b + (((size_t)b * 32 + iy) * 32 + ixx) * 128 + cig * 32 + q * 8);
            else
                *dst = (uint4){0u, 0u, 0u, 0u};
        }
        __syncthreads();
        #pragma unroll
        for (int tp = 0; tp < 4; ++tp) {
            const unsigned short* bp = wt + ((((p * 4 + tp) * 4 + cig) * 4 + hi) * 16 + lr) * 8;
            bf16x8 bF = *(const bf16x8*)bp;
            #pragma unroll
            for (int mf = 0; mf < 4; ++mf) {
                int pos = wv * 64 + mf * 16 + lr;
                int myl = pos >> 5, mx = pos & 31;
                int l = myl + a + (tp < 2 ? 1 : 0);
                int xx = mx + bb + ((tp & 1) ? 0 : 1);
                bf16x8 aF = *(const bf16x8*)(sd + (l * 34 + xx) * 32 + hi * 8);
                acc[mf] = __builtin_amdgcn_mfma_f32_16x16x32_bf16(aF, bF, acc[mf], 0, 0, 0);
            }
        }
    }
    if (lr < 3) {
        float bv = bias[lr];
        #pragma unroll
        for (int mf = 0; mf < 4; ++mf) {
            #pragma unroll
            for (int r = 0; r < 4; ++r) {
                int pos = wv * 64 + mf * 16 + hi * 4 + r;
                int oy = 2 * (yh * 16 + (pos >> 5)) + a;
                int ox = 2 * (pos & 31) + bb;
                xhat[(((size_t)b * 3 + lr) * 64 + oy) * 64 + ox] = acc[mf][r] + bv;
            }
        }
    }
}

// ---------------- finalize: loss + perplexity ------------------------------
__global__ void k_final(const int* __restrict__ counts, const float* __restrict__ sse,
                        float* __restrict__ out_loss, float* __restrict__ out_perp) {
    __shared__ float red[256];
    int tid = threadIdx.x;
    float s = 0.f;
    for (int k = tid; k < 1024; k += 256) {
        float p = (float)counts[k] * (1.f / 32768.f);
        s += p * logf(p + 1e-10f);
    }
    red[tid] = s;
    __syncthreads();
    for (int st = 128; st > 0; st >>= 1) {
        if (tid < st) red[tid] += red[tid + st];
        __syncthreads();
    }
    if (tid == 0) {
        *out_perp = expf(-red[0]);
        *out_loss = 0.25f * (*sse) / 8388608.0f;
    }
}

extern "C" void kernel_launch(void* const* d_in, const int* in_sizes, int n_in,
                              void* d_out, int out_size, void* d_ws, size_t ws_size,
                              hipStream_t stream) {
    const float* x   = (const float*)d_in[0];
    const float* ew1 = (const float*)d_in[1];
    const float* eb1 = (const float*)d_in[2];
    const float* ew2 = (const float*)d_in[3];
    const float* eb2 = (const float*)d_in[4];
    const float* dw1 = (const float*)d_in[5];
    const float* db1 = (const float*)d_in[6];
    const float* dw2 = (const float*)d_in[7];
    const float* db2 = (const float*)d_in[8];
    const float* cb  = (const float*)d_in[9];

    float* out  = (float*)d_out;
    float* xhat = out;                       // 128*3*64*64 = 1572864
    float* loss = out + 1572864;
    float* perp = out + 1572865;
    float* oh   = out + 1572866;             // 128*1024*256 = 33554432

    char* ws = (char*)d_ws;
    unsigned short* hA = (unsigned short*)ws;                 // 64 MB (dead after conv2)
    float* e      = (float*)(ws + (size_t)64 * 1024 * 1024);  // 32 MB (dead after vq)
    int*   idx    = (int*)(ws + (size_t)96 * 1024 * 1024);    // 128 KB
    int*   counts = idx + NLAT;                               // 4 KB
    float* sse    = (float*)(counts + KCB);                   // 4 B
    float* cn     = sse + 1;                                  // 4 KB
    unsigned short* cbp = (unsigned short*)ws;                // 1 MB (after conv2)
    unsigned short* d1b = (unsigned short*)ws;                // 32 MB (after vq; clobbers cbp)
    unsigned short* cbb = (unsigned short*)e;                 // 512 KB (after vq)
    unsigned short* wpk = (unsigned short*)(ws + (size_t)65 * 1024 * 1024);  // 1 MB (after vq)
    unsigned short* wt  = (unsigned short*)(ws + (size_t)67 * 1024 * 1024);  // 64 KB (after vq)
    unsigned short* wpf = (unsigned short*)(((uintptr_t)oh + 15) & ~(uintptr_t)15);  // 2 MB in oh region

    hipMemsetAsync(counts, 0, KCB * 4 + 4, stream);

    k_cnorm<<<4, 256, 0, stream>>>(cb, cn);
    k_packwf<<<128, 256, 0, stream>>>(ew2, wpf);               // dirties oh[0:2MB]
    k_conv1<<<dim3(8, 128), 256, 0, stream>>>(x, ew1, eb1, hA);
    k_zero_oh<<<2048, 256, 0, stream>>>(oh + 524304, (33554432 - 524304) / 4);  // beyond wpf slice
    k_conv2_mfma<<<dim3(4, 128), 512, 0, stream>>>(hA, wpf, eb2, e);
    k_zero_oh<<<64, 256, 0, stream>>>(oh, 524304 / 4);          // re-zero wpf slice
    k_packcbp<<<1024, 256, 0, stream>>>(cb, cbp);              // hA region now dead
    k_vq_mfma<<<512, 512, 0, stream>>>(e, cbp, cn, cb, idx, counts, sse, oh);
    k_cb2bf<<<256, 256, 0, stream>>>(cb, cbb);
    k_packw<<<128, 256, 0, stream>>>(dw1, wpk);
    k_packw2t<<<128, 256, 0, stream>>>(dw2, wt);
    k_convt1_mfma<<<dim3(4, 128), 512, 0, stream>>>(idx, cbb, wpk, db1, d1b);  // clobbers cbp (dead)
    k_convt2_mfma<<<dim3(8, 128), 512, 0, stream>>>(d1b, wt, db2, xhat);
    k_final<<<1, 256, 0, stream>>>(counts, sse, loss, perp);
}